// Round 2
// baseline (296.380 us; speedup 1.0000x reference)
//
#include <hip/hip_runtime.h>
#include <math.h>

typedef float f32x4 __attribute__((ext_vector_type(4)));

constexpr int kB = 8;
constexpr int kS = 4096;
constexpr int kF = 128;
constexpr int kT = 16;
constexpr int kNCHUNK = 256;           // S-chunks for the partial reduction
constexpr int kSCHUNK = kS / kNCHUNK;  // 16 s-steps per chunk
constexpr int kRows = 32;              // s-rows per spike block

// ---------------- Kernel A1: partial sums of diff / diff^2 per (chunk,b,f) ----
// 2048 blocks x 128 threads; 16 independent row loads per block -> ~1 HBM trip.
__global__ __launch_bounds__(128) void std_partial_kernel(
    const float* __restrict__ x, double* __restrict__ psum, double* __restrict__ psq) {
    const int b = blockIdx.x / kNCHUNK;
    const int c = blockIdx.x % kNCHUNK;
    const int f = threadIdx.x;  // 0..127
    const long base = ((long)(b * kS + c * kSCHUNK)) * kF + f;
    // diff at global s==0 is 0 (prepend), which falls out of prev = x[s=0].
    float prev = (c == 0) ? x[(long)b * kS * kF + f] : x[base - kF];
    float cur[kSCHUNK];
    #pragma unroll
    for (int j = 0; j < kSCHUNK; ++j) cur[j] = x[base + (long)j * kF];
    double s1 = 0.0, s2 = 0.0;
    #pragma unroll
    for (int j = 0; j < kSCHUNK; ++j) {
        float d = cur[j] - prev;   // exact f32 diff, matches reference
        s1 += (double)d;
        s2 += (double)d * (double)d;
        prev = cur[j];
    }
    const int o = c * (kB * kF) + b * kF + f;
    psum[o] = s1;
    psq[o]  = s2;
}

// ---------------- Kernel A2: finish std, store denom = std_f32 + 1e-8f -------
__global__ __launch_bounds__(256) void std_finish_kernel(
    const double* __restrict__ psum, const double* __restrict__ psq,
    float* __restrict__ denom) {
    const int i = blockIdx.x * blockDim.x + threadIdx.x;  // [0, kB*kF)
    if (i >= kB * kF) return;
    double s1 = 0.0, s2 = 0.0;
    for (int c = 0; c < kNCHUNK; ++c) {
        s1 += psum[c * (kB * kF) + i];
        s2 += psq[c * (kB * kF) + i];
    }
    const double mean = s1 / (double)kS;
    double var = s2 / (double)kS - mean * mean;
    if (var < 0.0) var = 0.0;
    const float stdf = (float)sqrt(var);   // double->f32 once, like np.std f32 result
    denom[i] = stdf + 1e-8f;               // f32 add, matches (std + EPS)
}

// ---------------- Fallback: direct std if ws too small (deterministic) -------
__global__ __launch_bounds__(128) void std_direct_kernel(
    const float* __restrict__ x, float* __restrict__ denom) {
    const int b = blockIdx.x;
    const int f = threadIdx.x;
    const long base = (long)b * kS * kF + f;
    float prev = x[base];
    double s1 = 0.0, s2 = 0.0;
    for (int s = 0; s < kS; ++s) {
        float cur = x[base + (long)s * kF];
        float d = cur - prev;
        s1 += (double)d;
        s2 += (double)d * (double)d;
        prev = cur;
    }
    const double mean = s1 / (double)kS;
    double var = s2 / (double)kS - mean * mean;
    if (var < 0.0) var = 0.0;
    denom[b * kF + f] = (float)sqrt(var) + 1e-8f;
}

// ---------------- Kernel B: pos/neg once into LDS, 16 KB contiguous writes ---
// block = 256 threads; each block owns 32 s-rows of one b.
// grid  = kB * (kS/32) = 1024 blocks.
__global__ __launch_bounds__(256) void spike_write_kernel(
    const float* __restrict__ x, const float* __restrict__ denom,
    float* __restrict__ out) {
    __shared__ float pos_s[kRows * kF];   // 16 KB
    __shared__ float neg_s[kRows * kF];   // 16 KB
    const int tid = threadIdx.x;
    const int f4 = tid & 31;          // float4 index along F
    const int sl = tid >> 5;          // 0..7
    const int b  = blockIdx.x >> 7;   // 128 s-chunks per b
    const int sc = blockIdx.x & 127;
    const int s0 = sc * kRows;

    const f32x4 dn = *(const f32x4*)(denom + b * kF + f4 * 4);

    #pragma unroll
    for (int r = sl; r < kRows; r += 8) {
        const int s = s0 + r;
        const long off = ((long)(b * kS + s)) * kF + f4 * 4;
        const f32x4 cur  = *(const f32x4*)(x + off);
        const f32x4 prev = (s == 0) ? cur : *(const f32x4*)(x + off - kF);
        f32x4 p, n;
        #pragma unroll
        for (int k = 0; k < 4; ++k) {
            const float nd = (cur[k] - prev[k]) / dn[k];  // f32 div, like reference
            p[k] = (nd  >= 0.1f) ? 1.0f : 0.0f;
            n[k] = (-nd >= 0.1f) ? 1.0f : 0.0f;
        }
        *(f32x4*)(pos_s + r * kF + f4 * 4) = p;
        *(f32x4*)(neg_s + r * kF + f4 * 4) = n;
    }
    __syncthreads();

    f32x4 zero;
    zero[0] = 0.0f; zero[1] = 0.0f; zero[2] = 0.0f; zero[3] = 0.0f;

    const long slice = (long)kS * kF;
    const long outb = (((long)b * kT) * kS + s0) * kF;
    for (int t = 0; t < kT; ++t) {
        const int ph = t % 3;  // 0 -> pos, 1 -> neg, 2 -> silent
        float* dst = out + outb + (long)t * slice;
        if (ph == 2) {
            #pragma unroll
            for (int i = 0; i < 4; ++i)
                *(f32x4*)(dst + (i * 256 + tid) * 4) = zero;
        } else {
            const float* src = (ph == 0) ? pos_s : neg_s;
            #pragma unroll
            for (int i = 0; i < 4; ++i) {
                const f32x4 v = *(const f32x4*)(src + (i * 256 + tid) * 4);
                *(f32x4*)(dst + (i * 256 + tid) * 4) = v;
            }
        }
    }
}

extern "C" void kernel_launch(void* const* d_in, const int* in_sizes, int n_in,
                              void* d_out, int out_size, void* d_ws, size_t ws_size,
                              hipStream_t stream) {
    const float* x = (const float*)d_in[0];
    float* out = (float*)d_out;

    // ws layout: [0,4KB) denom floats (1024); then 8B-aligned partial doubles
    float* denom = (float*)d_ws;
    double* psum = (double*)((char*)d_ws + 4096);
    double* psq  = psum + (size_t)kNCHUNK * kB * kF;
    const size_t needed = 4096 + 2ull * kNCHUNK * kB * kF * sizeof(double);

    if (ws_size >= needed) {
        std_partial_kernel<<<kB * kNCHUNK, 128, 0, stream>>>(x, psum, psq);
        std_finish_kernel<<<(kB * kF + 255) / 256, 256, 0, stream>>>(psum, psq, denom);
    } else {
        std_direct_kernel<<<kB, 128, 0, stream>>>(x, denom);
    }
    spike_write_kernel<<<kB * (kS / kRows), 256, 0, stream>>>(x, denom, out);
}

// Round 3
// 291.741 us; speedup vs baseline: 1.0159x; 1.0159x over previous
//
#include <hip/hip_runtime.h>
#include <math.h>

typedef float f32x4 __attribute__((ext_vector_type(4)));

constexpr int kB = 8;
constexpr int kS = 4096;
constexpr int kF = 128;
constexpr int kT = 16;
constexpr int kNCHUNK = 256;           // S-chunks for the partial reduction
constexpr int kSCHUNK = kS / kNCHUNK;  // 16 s-steps per chunk
constexpr int kRows = 32;              // s-rows per spike block

// ---------------- Kernel A1: partial sums of diff / diff^2 per (chunk,b,f) ----
__global__ __launch_bounds__(128) void std_partial_kernel(
    const float* __restrict__ x, double* __restrict__ psum, double* __restrict__ psq) {
    const int b = blockIdx.x / kNCHUNK;
    const int c = blockIdx.x % kNCHUNK;
    const int f = threadIdx.x;  // 0..127
    const long base = ((long)(b * kS + c * kSCHUNK)) * kF + f;
    // diff at global s==0 is 0 (prepend), which falls out of prev = x[s=0].
    float prev = (c == 0) ? x[(long)b * kS * kF + f] : x[base - kF];
    float cur[kSCHUNK];
    #pragma unroll
    for (int j = 0; j < kSCHUNK; ++j) cur[j] = x[base + (long)j * kF];
    double s1 = 0.0, s2 = 0.0;
    #pragma unroll
    for (int j = 0; j < kSCHUNK; ++j) {
        float d = cur[j] - prev;   // exact f32 diff, matches reference
        s1 += (double)d;
        s2 += (double)d * (double)d;
        prev = cur[j];
    }
    const int o = c * (kB * kF) + b * kF + f;
    psum[o] = s1;
    psq[o]  = s2;
}

// ---------------- Kernel A2: finish std, store denom = std_f32 + 1e-8f -------
__global__ __launch_bounds__(256) void std_finish_kernel(
    const double* __restrict__ psum, const double* __restrict__ psq,
    float* __restrict__ denom) {
    const int i = blockIdx.x * blockDim.x + threadIdx.x;  // [0, kB*kF)
    if (i >= kB * kF) return;
    double s1 = 0.0, s2 = 0.0;
    for (int c = 0; c < kNCHUNK; ++c) {
        s1 += psum[c * (kB * kF) + i];
        s2 += psq[c * (kB * kF) + i];
    }
    const double mean = s1 / (double)kS;
    double var = s2 / (double)kS - mean * mean;
    if (var < 0.0) var = 0.0;
    const float stdf = (float)sqrt(var);   // double->f32 once, like np.std f32 result
    denom[i] = stdf + 1e-8f;               // f32 add, matches (std + EPS)
}

// ---------------- Fallback: direct std if ws too small (deterministic) -------
__global__ __launch_bounds__(128) void std_direct_kernel(
    const float* __restrict__ x, float* __restrict__ denom) {
    const int b = blockIdx.x;
    const int f = threadIdx.x;
    const long base = (long)b * kS * kF + f;
    float prev = x[base];
    double s1 = 0.0, s2 = 0.0;
    for (int s = 0; s < kS; ++s) {
        float cur = x[base + (long)s * kF];
        float d = cur - prev;
        s1 += (double)d;
        s2 += (double)d * (double)d;
        prev = cur;
    }
    const double mean = s1 / (double)kS;
    double var = s2 / (double)kS - mean * mean;
    if (var < 0.0) var = 0.0;
    denom[b * kF + f] = (float)sqrt(var) + 1e-8f;
}

// ---------------- Kernel B: zeros first, then pos/neg grouped, NT stores -----
// block = 256 threads; each block owns 32 s-rows of one b.
// grid  = kB * (kS/32) = 1024 blocks.
__global__ __launch_bounds__(256) void spike_write_kernel(
    const float* __restrict__ x, const float* __restrict__ denom,
    float* __restrict__ out) {
    __shared__ float pos_s[kRows * kF];   // 16 KB
    __shared__ float neg_s[kRows * kF];   // 16 KB
    const int tid = threadIdx.x;
    const int f4 = tid & 31;          // float4 index along F
    const int sl = tid >> 5;          // 0..7
    const int b  = blockIdx.x >> 7;   // 128 s-chunks per b
    const int sc = blockIdx.x & 127;
    const int s0 = sc * kRows;

    const long slice = (long)kS * kF;
    const long outb = (((long)b * kT) * kS + s0) * kF;

    // --- Phase 0: t%3==2 slices are constant zero -> write them immediately,
    //     before any load dependency, so these 84 MB stream while we compute.
    f32x4 zero;
    zero[0] = 0.0f; zero[1] = 0.0f; zero[2] = 0.0f; zero[3] = 0.0f;
    #pragma unroll
    for (int z = 0; z < 5; ++z) {                 // t = 2,5,8,11,14
        float* dst = out + outb + (long)(3 * z + 2) * slice;
        #pragma unroll
        for (int i = 0; i < 4; ++i)
            __builtin_nontemporal_store(zero, (f32x4*)(dst + (i * 256 + tid) * 4));
    }

    // --- Phase 1: compute pos/neg spikes into LDS.
    const f32x4 dn = *(const f32x4*)(denom + b * kF + f4 * 4);
    #pragma unroll
    for (int r = sl; r < kRows; r += 8) {
        const int s = s0 + r;
        const long off = ((long)(b * kS + s)) * kF + f4 * 4;
        const f32x4 cur  = *(const f32x4*)(x + off);
        const f32x4 prev = (s == 0) ? cur : *(const f32x4*)(x + off - kF);
        f32x4 p, n;
        #pragma unroll
        for (int k = 0; k < 4; ++k) {
            const float nd = (cur[k] - prev[k]) / dn[k];  // f32 div, like reference
            p[k] = (nd  >= 0.1f) ? 1.0f : 0.0f;
            n[k] = (-nd >= 0.1f) ? 1.0f : 0.0f;
        }
        *(f32x4*)(pos_s + r * kF + f4 * 4) = p;
        *(f32x4*)(neg_s + r * kF + f4 * 4) = n;
    }
    __syncthreads();

    // --- Phase 2: pos slices (t%3==0: t=0,3,6,9,12,15), read LDS once per i,
    //     fan out to all 6 slices -> long store bursts, few LDS round-trips.
    #pragma unroll
    for (int i = 0; i < 4; ++i) {
        const f32x4 v = *(const f32x4*)(pos_s + (i * 256 + tid) * 4);
        #pragma unroll
        for (int z = 0; z < 6; ++z) {
            float* dst = out + outb + (long)(3 * z) * slice;
            __builtin_nontemporal_store(v, (f32x4*)(dst + (i * 256 + tid) * 4));
        }
    }
    // --- Phase 3: neg slices (t%3==1: t=1,4,7,10,13).
    #pragma unroll
    for (int i = 0; i < 4; ++i) {
        const f32x4 v = *(const f32x4*)(neg_s + (i * 256 + tid) * 4);
        #pragma unroll
        for (int z = 0; z < 5; ++z) {
            float* dst = out + outb + (long)(3 * z + 1) * slice;
            __builtin_nontemporal_store(v, (f32x4*)(dst + (i * 256 + tid) * 4));
        }
    }
}

extern "C" void kernel_launch(void* const* d_in, const int* in_sizes, int n_in,
                              void* d_out, int out_size, void* d_ws, size_t ws_size,
                              hipStream_t stream) {
    const float* x = (const float*)d_in[0];
    float* out = (float*)d_out;

    // ws layout: [0,4KB) denom floats (1024); then 8B-aligned partial doubles
    float* denom = (float*)d_ws;
    double* psum = (double*)((char*)d_ws + 4096);
    double* psq  = psum + (size_t)kNCHUNK * kB * kF;
    const size_t needed = 4096 + 2ull * kNCHUNK * kB * kF * sizeof(double);

    if (ws_size >= needed) {
        std_partial_kernel<<<kB * kNCHUNK, 128, 0, stream>>>(x, psum, psq);
        std_finish_kernel<<<(kB * kF + 255) / 256, 256, 0, stream>>>(psum, psq, denom);
    } else {
        std_direct_kernel<<<kB, 128, 0, stream>>>(x, denom);
    }
    spike_write_kernel<<<kB * (kS / kRows), 256, 0, stream>>>(x, denom, out);
}